// Round 10
// baseline (281.919 us; speedup 1.0000x reference)
//
#include <hip/hip_runtime.h>
#include <math.h>

// InputMPNN on MI355X — v7: MEASUREMENT PROBE (v5 + fused body rep x4).
// Purpose: isolate fused's true cost (Δdur = 3 x fused) and, if fused >= ~41us,
// surface it in rocprof top-5 WITH counters. Idempotent: each rep recomputes
// Q/X/H in LDS and rewrites identical out. Race-free across reps: the last
// __syncthreads precedes mlp2 (reads H only); rep r+1 before its first sync
// writes only Q and X-upper, which have no readers past that point.

typedef __attribute__((ext_vector_type(8))) short bf16x8;
typedef __attribute__((ext_vector_type(4))) float f32x4;
typedef unsigned short u16;

#define BB 8
#define NN 256
#define CC 128

__device__ __forceinline__ u16 f2bf(float f) {
    union { float f; unsigned int u; } v; v.f = f;
    unsigned int u = v.u;
    return (u16)((u + 0x7FFFu + ((u >> 16) & 1u)) >> 16);   // RNE
}

#define MFMA(a, b, c) __builtin_amdgcn_mfma_f32_16x16x32_bf16((a), (b), (c), 0, 0, 0)

// ---------------- prep: transposes + bf16 converts (all pre-swizzled) -------
__global__ __launch_bounds__(256) void prep_kernel(
    const float* __restrict__ features, const float* __restrict__ W1,
    const float* __restrict__ W2, u16* __restrict__ Ft,
    u16* __restrict__ W1t, u16* __restrict__ W2t)
{
    __shared__ float S[64][65];
    const int blk = blockIdx.x, t = threadIdx.x;
    if (blk < 64) {                    // Ft[b][c][x^] = features[b][x][c]
        const int b = blk >> 3, tl = blk & 7, c0 = (tl >> 2) * 64, x0 = (tl & 3) * 64;
        const int j = t & 63, ri = t >> 6;
#pragma unroll
        for (int rr = 0; rr < 16; ++rr) {
            int xl = rr * 4 + ri;
            S[j][xl] = features[(size_t)(b * NN + x0 + xl) * CC + c0 + j];
        }
        __syncthreads();
#pragma unroll
        for (int rr = 0; rr < 16; ++rr) {
            int cl = rr * 4 + ri;
            int c = c0 + cl, x = x0 + j;
            Ft[(size_t)(b * CC + c) * NN + (x ^ ((c & 7) << 3))] = f2bf(S[cl][j]);
        }
    } else {                           // W1t/W2t[n][k^] = W[k][n]
        const int isW2 = (blk >= 80), tl = (blk - 64) & 15;
        const int n0 = (tl >> 2) * 64, k0 = (tl & 3) * 64;
        const float* W = isW2 ? W2 : W1;
        u16* Wt = isW2 ? W2t : W1t;
        const int j = t & 63, ri = t >> 6;
#pragma unroll
        for (int rr = 0; rr < 16; ++rr) {
            int kl = rr * 4 + ri;
            S[j][kl] = W[(size_t)(k0 + kl) * 256 + n0 + j];
        }
        __syncthreads();
#pragma unroll
        for (int rr = 0; rr < 16; ++rr) {
            int nl = rr * 4 + ri;
            int n = n0 + nl, k = k0 + j;
            Wt[(size_t)n * 256 + (k ^ ((n & 7) << 3))] = f2bf(S[nl][j]);
        }
    }
}

// ---------------- fused (v5 structure) with internal rep x4 -----------------
__global__ __launch_bounds__(512, 1) void fused_kernel(
    const float* __restrict__ norms, const float* __restrict__ features,
    const u16* __restrict__ Ft,
    const float* __restrict__ rad_W, const float* __restrict__ rad_b,
    const u16* __restrict__ W1t, const float* __restrict__ b1,
    const u16* __restrict__ W2t, const float* __restrict__ b2,
    float* __restrict__ out)
{
    __shared__ __align__(16) char Q[8][16384];     // 128 KB: 8 a-tiles
    __shared__ __align__(16) u16 X[16][256];       // 8 KB
    __shared__ __align__(16) u16 H[16][256];       // 8 KB

    const int bid = blockIdx.x;
    const int swz = (bid & 7) * 32 + (bid >> 3);
    const int b = swz >> 5, a0 = (swz & 31) * 8;

    const int t = threadIdx.x, w = t >> 6, lane = t & 63;
    const int g = lane >> 4, rA = lane & 15;
    const int wq = w & 3, grp = w >> 2;

    // ---- F K-slices into registers (loop-invariant) ----
    bf16x8 Freg[8][2];
    {
        const u16* fb = Ft + (size_t)b * 32768;
#pragma unroll
        for (int kq = 0; kq < 8; ++kq)
#pragma unroll
            for (int n = 0; n < 2; ++n) {
                int c = 32 * wq + 16 * n + rA;
                int xb = 32 * kq + 8 * g;
                Freg[kq][n] = *(const bf16x8*)(fb + (size_t)c * 256 + (xb ^ ((c & 7) << 3)));
            }
    }

    // ---- W' into registers (loop-invariant) ----
    float Wreg[2][2][4];
#pragma unroll
    for (int m = 0; m < 2; ++m)
#pragma unroll
        for (int n = 0; n < 2; ++n)
#pragma unroll
            for (int r = 0; r < 4; ++r) {
                const int kb = 16 * m + 4 * g + r;
                const int c = 32 * wq + 16 * n + rA;
                float v;
                if (kb < 28)       v = rad_W[(size_t)(kb + 4) * CC + c];
                else if (kb == 28) v = rad_b[c];
                else               v = 0.f;
                Wreg[m][n][r] = v;
            }

#pragma unroll 1
    for (int rep = 0; rep < 4; ++rep) {

    // ---- zero Q rows 29..31 of all 8 tiles ----
#pragma unroll
    for (int i = 0; i < 6; ++i) {
        int idx = t + i * 512;                     // 3072 u32 = 8 x 3 x 128
        int tile = idx / 384, rm = idx - tile * 384;
        *(unsigned int*)(Q[tile] + 29 * 512 + rm * 4) = 0u;
    }

    // ---- build Q: thread handles x = t&255 for its group's 4 tiles ----
    {
        const int xq = t & 255, qg = t >> 8;
#pragma unroll
        for (int ia = 0; ia < 4; ++ia) {
            const float r_ = norms[((size_t)(b * NN + a0 + qg * 4 + ia)) * NN + xq];
            const float ir = 1.0f / r_;
            float s1, c1v;
            __sincosf(6.28318530717958647692f * r_, &s1, &c1v);
            const float s2 = 2.0f * s1 * c1v, c2 = c1v * c1v - s1 * s1;
            const float s3 = s1 * c2 + c1v * s2, c3 = c1v * c2 - s1 * s2;
            float cut = 0.0f;
            if (r_ < 1.73f) cut = 1.0f / (1.0f + __expf((r_ - 1.73f) * 5.0f));
            const float tv[7] = { s1, s2, s3, 1.0f, c1v, c2, c3 };
            const float po[4] = { cut, cut * ir, cut * ir * ir, cut * ir * ir * ir };
            char* qn = Q[qg * 4 + ia];
#pragma unroll
            for (int i = 0; i < 7; ++i)
#pragma unroll
                for (int pw = 0; pw < 4; ++pw) {
                    int kb = i * 4 + pw;
                    *(u16*)(qn + kb * 512 + ((2 * xq) ^ ((kb & 7) << 4))) =
                        f2bf(tv[i] * po[pw]);
                }
            *(u16*)(qn + 28 * 512 + ((2 * xq) ^ ((28 & 7) << 4))) = f2bf(cut);
        }
    }

    // ---- features -> X upper half (k = 128+c) ----
#pragma unroll
    for (int i = 0; i < 2; ++i) {
        int e = t + i * 512;                       // 1024 = 8 rows x 128 c
        int row = e >> 7, c = e & 127;
        float v = features[(size_t)(b * NN + a0 + row) * CC + c];
        X[row][(128 + c) ^ ((row & 7) << 3)] = f2bf(v);
    }
    __syncthreads();

    // ---- fmp MFMA + register epilogue -> X lower half ----
#pragma unroll 1
    for (int ia = 0; ia < 4; ++ia) {
        const char* q = Q[grp * 4 + ia];
        f32x4 acc[2][2] = {};
#pragma unroll
        for (int kq = 0; kq < 8; ++kq) {
            const int inner = (kq * 64 + g * 16) ^ ((rA & 7) << 4);
            bf16x8 A0 = *(const bf16x8*)(q + rA * 512 + inner);
            bf16x8 A1 = *(const bf16x8*)(q + (16 + rA) * 512 + inner);
            acc[0][0] = MFMA(A0, Freg[kq][0], acc[0][0]);
            acc[0][1] = MFMA(A0, Freg[kq][1], acc[0][1]);
            acc[1][0] = MFMA(A1, Freg[kq][0], acc[1][0]);
            acc[1][1] = MFMA(A1, Freg[kq][1], acc[1][1]);
        }
        float P0 = 0.f, P1 = 0.f;
#pragma unroll
        for (int m = 0; m < 2; ++m)
#pragma unroll
            for (int r = 0; r < 4; ++r) {
                P0 = fmaf(Wreg[m][0][r], acc[m][0][r], P0);
                P1 = fmaf(Wreg[m][1][r], acc[m][1][r], P1);
            }
        P0 += __shfl_xor(P0, 16); P0 += __shfl_xor(P0, 32);
        P1 += __shfl_xor(P1, 16); P1 += __shfl_xor(P1, 32);
        if (g == 0) {
            const int row = grp * 4 + ia;
            const int c0 = 32 * wq + rA, c1 = c0 + 16;
            X[row][c0 ^ ((row & 7) << 3)] = f2bf(P0);
            X[row][c1 ^ ((row & 7) << 3)] = f2bf(P1);
        }
    }
    __syncthreads();

    // ---- mlp1: A = X (LDS), B = W1t (global), H -> LDS ----
    {
        f32x4 acc[2] = {};
#pragma unroll
        for (int k0 = 0; k0 < 8; ++k0) {
            const int ke = (k0 * 32 + 8 * g);
            bf16x8 A = *(const bf16x8*)(&X[rA][ke ^ ((rA & 7) << 3)]);
#pragma unroll
            for (int nt = 0; nt < 2; ++nt) {
                const int col = 32 * w + 16 * nt + rA;
                bf16x8 Bv = *(const bf16x8*)(W1t + (size_t)col * 256 + (ke ^ ((col & 7) << 3)));
                acc[nt] = MFMA(A, Bv, acc[nt]);
            }
        }
#pragma unroll
        for (int nt = 0; nt < 2; ++nt)
#pragma unroll
            for (int r = 0; r < 4; ++r) {
                const int row = 4 * g + r;
                const int col = 32 * w + 16 * nt + rA;
                float v = acc[nt][r] + b1[col];
                v = (v > 0.f) ? v : 0.01f * v;
                H[row][col ^ ((row & 7) << 3)] = f2bf(v);
            }
    }
    __syncthreads();

    // ---- mlp2: A = H (LDS), B = W2t (global), store out ----
    {
        f32x4 acc[2] = {};
#pragma unroll
        for (int k0 = 0; k0 < 8; ++k0) {
            const int ke = (k0 * 32 + 8 * g);
            bf16x8 A = *(const bf16x8*)(&H[rA][ke ^ ((rA & 7) << 3)]);
#pragma unroll
            for (int nt = 0; nt < 2; ++nt) {
                const int col = 32 * w + 16 * nt + rA;
                bf16x8 Bv = *(const bf16x8*)(W2t + (size_t)col * 256 + (ke ^ ((col & 7) << 3)));
                acc[nt] = MFMA(A, Bv, acc[nt]);
            }
        }
#pragma unroll
        for (int nt = 0; nt < 2; ++nt)
#pragma unroll
            for (int r = 0; r < 4; ++r) {
                const int row = 4 * g + r;
                if (row < 8) {
                    const int col = 32 * w + 16 * nt + rA;
                    out[(size_t)(b * NN + a0 + row) * 256 + col] = acc[nt][r] + b2[col];
                }
            }
    }
    __syncthreads();   // rep boundary: H fully consumed before next rep

    }  // rep
}

extern "C" void kernel_launch(void* const* d_in, const int* in_sizes, int n_in,
                              void* d_out, int out_size, void* d_ws, size_t ws_size,
                              hipStream_t stream) {
    const float* features = (const float*)d_in[0];
    const float* norms    = (const float*)d_in[4];
    const float* rad_W    = (const float*)d_in[5];
    const float* rad_b    = (const float*)d_in[6];
    const float* W1       = (const float*)d_in[7];
    const float* b1       = (const float*)d_in[8];
    const float* W2       = (const float*)d_in[9];
    const float* b2       = (const float*)d_in[10];

    char* ws = (char*)d_ws;
    u16* Ft  = (u16*)ws;                  // 512 KB
    u16* W1t = (u16*)(ws + 524288);       // 128 KB
    u16* W2t = (u16*)(ws + 524288 + 131072);

    prep_kernel<<<96, 256, 0, stream>>>(features, W1, W2, Ft, W1t, W2t);
    fused_kernel<<<256, 512, 0, stream>>>(norms, features, Ft, rad_W, rad_b,
                                          W1t, b1, W2t, b2, (float*)d_out);
}